// Round 7
// baseline (86.650 us; speedup 1.0000x reference)
//
#include <hip/hip_runtime.h>
#include <math.h>

#define NB 64
#define NP 8732
#define NC 81
#define NROWS (NB * NP)             // 558848
#define RPB 32                      // rows per block-tile (8 per wave)
#define TPB 256
#define NTILES (NROWS / RPB)        // 17464 (exact)
#define GRID 1536                   // 6 blocks/CU x 256 CU = exact residency
#define SLICE_FLOATS (8 * NC)       // 648 floats = 2592 B per wave slice
#define SLICE_F4 (SLICE_FLOATS / 4) // 162 = 64 + 64 + 34
#define MAX_IT ((NTILES + GRID - 1) / GRID)   // 12
#define KPT 35                      // ceil(NP/256); i=34 valid only for tid<28

// ws layout:
//   acc : double[8]     @ 0   [0]=topK_neg [1]=ce_pos [2]=sl1 [3]=num_pos [4]=ticket
//   bg  : float[NROWS]  @ 64
//   lse : float[NROWS]  @ 64 + NROWS*4
#define BG_OFF  64
#define LSE_OFF (BG_OFF + NROWS * 4)

__global__ __launch_bounds__(TPB) void mb_rows(
    const float* __restrict__ conf,
    float* __restrict__ bg,
    float* __restrict__ lse_out,
    double* __restrict__ acc)
{
    __shared__ __align__(16) float sbuf[4 * 2 * SLICE_FLOATS];  // 20736 B
    __shared__ float2 stash[MAX_IT * RPB];                      // 3072 B

    const int tid  = threadIdx.x;
    const int w    = tid >> 6;
    const int lane = tid & 63;

    if (blockIdx.x == 0 && tid == 0) {
        acc[0] = 0.0; acc[1] = 0.0; acc[2] = 0.0; acc[3] = 0.0; acc[4] = 0.0;
    }

    const int r   = lane >> 3;      // 0..7 row within wave slice
    const int h   = lane & 7;       // eighth-of-row
    const int off = h * 10;         // h==7 also covers elem 80

    // wave-private DMA of one 8-row slice into sbuf[w][p] (linear lane order)
    auto stage = [&](int t, int p) {
        const float4* s4 = (const float4*)(conf + (size_t)t * (RPB * NC) + w * SLICE_FLOATS);
        float4*       d4 = (float4*)&sbuf[(w * 2 + p) * SLICE_FLOATS];
#if __has_builtin(__builtin_amdgcn_global_load_lds)
        __builtin_amdgcn_global_load_lds(
            (const __attribute__((address_space(1))) void*)(s4 + lane),
            (__attribute__((address_space(3))) void*)(d4 + lane), 16, 0, 0);
        __builtin_amdgcn_global_load_lds(
            (const __attribute__((address_space(1))) void*)(s4 + 64 + lane),
            (__attribute__((address_space(3))) void*)(d4 + 64 + lane), 16, 0, 0);
        if (lane < SLICE_F4 - 128)
            __builtin_amdgcn_global_load_lds(
                (const __attribute__((address_space(1))) void*)(s4 + 128 + lane),
                (__attribute__((address_space(3))) void*)(d4 + 128 + lane), 16, 0, 0);
#else
        d4[lane]      = s4[lane];
        d4[64 + lane] = s4[64 + lane];
        if (lane < SLICE_F4 - 128) d4[128 + lane] = s4[128 + lane];
#endif
    };

    int t = blockIdx.x;
    stage(t, 0);                     // GRID < NTILES: always valid

    int p = 0, it = 0;
    for (; t < NTILES; t += GRID, ++it) {
        const int tn = t + GRID;
        if (tn < NTILES) {
            stage(tn, p ^ 1);                            // keep 3 newest in flight
            asm volatile("s_waitcnt vmcnt(3)" ::: "memory");  // prev stage done
        } else {
            asm volatile("s_waitcnt vmcnt(0)" ::: "memory");  // last tile: drain
        }

        const float* rp = &sbuf[(w * 2 + p) * SLICE_FLOATS + r * NC];
        float v[11];
        #pragma unroll
        for (int j = 0; j < 10; ++j) v[j] = rp[off + j];
        v[10] = (h == 7) ? rp[80] : -__builtin_inff();

        float m = v[0];
        #pragma unroll
        for (int j = 1; j < 11; ++j) m = fmaxf(m, v[j]);
        m = fmaxf(m, __shfl_xor(m, 1));
        m = fmaxf(m, __shfl_xor(m, 2));
        m = fmaxf(m, __shfl_xor(m, 4));

        float s = 0.0f;
        #pragma unroll
        for (int j = 0; j < 11; ++j) s += __expf(v[j] - m);   // exp(-inf)=0
        s += __shfl_xor(s, 1);
        s += __shfl_xor(s, 2);
        s += __shfl_xor(s, 4);

        const float lse = m + __logf(s);

        if (h == 0)                               // LDS stash only — NO global ops
            stash[it * RPB + w * 8 + r] = make_float2(lse - v[0], lse);
        p ^= 1;
    }

    // ---- one-time flush of (bg, lse) ----
    __syncthreads();
    const int nit = (NTILES - blockIdx.x + GRID - 1) / GRID;
    for (int s = tid; s < nit * RPB; s += TPB) {
        const int i2 = s >> 5, rit = s & 31;
        const int row = (blockIdx.x + i2 * GRID) * RPB + rit;
        const float2 v2 = stash[s];
        bg[row]      = v2.x;
        lse_out[row] = v2.y;
    }
}

// One 256-thread block per batch row b:
//  (a) positive tail: ce_pos (lse - conf[g,lbl]), smooth-L1, num_pos
//  (b) exact top-K sum of bg among negatives (register keys, binary search)
//  (c) last block through the device-scope ticket writes the outputs.
__global__ __launch_bounds__(256) void mb_select(
    const float* __restrict__ conf,
    const float* __restrict__ pred,
    const float* __restrict__ gt,
    const int*   __restrict__ labels,
    const float* __restrict__ bg,
    const float* __restrict__ lse,
    double* __restrict__ acc,
    float* __restrict__ out)
{
    __shared__ unsigned cnt[32];
    __shared__ unsigned s_u[4][3];
    __shared__ double   s_d[4][2];
    __shared__ unsigned s_K, s_lo, s_hi;

    const int b = blockIdx.x, tid = threadIdx.x;
    const int lane = tid & 63, wid = tid >> 6;

    unsigned k[KPT];
    unsigned np = 0, maxk = 0u, mink = 0xFFFFFFFFu;
    double ce = 0.0, sl = 0.0;
    #pragma unroll
    for (int i = 0; i < KPT; ++i) {
        unsigned key = 0u;
        if (i < 34 || tid < 28) {
            const int g   = b * NP + i * 256 + tid;
            const int lbl = labels[g];
            const float vv = bg[g];
            key = (lbl > 0) ? 0u : (__float_as_uint(vv) + 1u);  // bg>=0: order-preserving
            if (lbl > 0) {
                np++;
                ce += (double)(lse[g] - conf[(size_t)g * NC + lbl]);
                const float4 pv = ((const float4*)pred)[g];
                const float4 gv = ((const float4*)gt)[g];
                float d;
                d = fabsf(pv.x - gv.x); sl += (d < 1.f) ? 0.5f * d * d : d - 0.5f;
                d = fabsf(pv.y - gv.y); sl += (d < 1.f) ? 0.5f * d * d : d - 0.5f;
                d = fabsf(pv.z - gv.z); sl += (d < 1.f) ? 0.5f * d * d : d - 0.5f;
                d = fabsf(pv.w - gv.w); sl += (d < 1.f) ? 0.5f * d * d : d - 0.5f;
            }
            if (key) { maxk = max(maxk, key); mink = min(mink, key); }
        }
        k[i] = key;
    }
    for (int i = tid; i < 32; i += 256) cnt[i] = 0u;

    #pragma unroll
    for (int o = 32; o; o >>= 1) {
        np   += __shfl_xor(np, o);
        maxk  = max(maxk, __shfl_xor(maxk, o));
        mink  = min(mink, __shfl_xor(mink, o));
        ce   += __shfl_xor(ce, o);
        sl   += __shfl_xor(sl, o);
    }
    if (lane == 0) {
        s_u[wid][0] = np; s_u[wid][1] = maxk; s_u[wid][2] = mink;
        s_d[wid][0] = ce; s_d[wid][1] = sl;
    }
    __syncthreads();

    if (tid == 0) {
        double pce = 0, psl = 0;
        unsigned npt = 0, mx = 0, mn = 0xFFFFFFFFu;
        for (int q = 0; q < 4; ++q) {
            pce += s_d[q][0]; psl += s_d[q][1];
            npt += s_u[q][0];
            mx = max(mx, s_u[q][1]); mn = min(mn, s_u[q][2]);
        }
        atomicAdd(&acc[1], pce);
        atomicAdd(&acc[2], psl);
        atomicAdd(&acc[3], (double)npt);
        unsigned K = 3u * npt;
        const unsigned nneg = NP - npt;
        if (K > nneg) K = nneg;
        s_K = K; s_lo = mn; s_hi = mx;
    }
    __syncthreads();

    const unsigned K = s_K;
    if (K > 0) {
        // smallest x with count(key > x) < K  ->  key of K-th largest
        unsigned lo = s_lo, hi = s_hi;
        int it = 0;
        while (lo < hi) {
            const unsigned mid = lo + ((hi - lo) >> 1);
            unsigned c = 0;
            #pragma unroll
            for (int i = 0; i < KPT; ++i) c += (k[i] > mid) ? 1u : 0u;
            #pragma unroll
            for (int o = 32; o; o >>= 1) c += __shfl_xor(c, o);
            if (lane == 0) atomicAdd(&cnt[it], c);
            __syncthreads();
            if (cnt[it] < K) hi = mid; else lo = mid + 1;
            ++it;
        }
        const unsigned V = lo;            // exact key of K-th largest (>=1)

        double ssum = 0.0; unsigned cgt = 0;
        #pragma unroll
        for (int i = 0; i < KPT; ++i) {
            const unsigned kk = k[i];
            if (kk > V) { ssum += (double)__uint_as_float(kk - 1u); cgt++; }
        }
        #pragma unroll
        for (int o = 32; o; o >>= 1) { ssum += __shfl_xor(ssum, o); cgt += __shfl_xor(cgt, o); }
        if (lane == 0) { s_d[wid][0] = ssum; s_u[wid][0] = cgt; }
        __syncthreads();
        if (tid == 0) {
            double tot = s_d[0][0] + s_d[1][0] + s_d[2][0] + s_d[3][0];
            const unsigned cg = s_u[0][0] + s_u[1][0] + s_u[2][0] + s_u[3][0];
            tot += (double)(K - cg) * (double)__uint_as_float(V - 1u);  // ties at V
            atomicAdd(&acc[0], tot);
        }
    }

    // ---- fused finalization: last block through the ticket writes out ----
    if (tid == 0) {
        __threadfence();
        const unsigned done = atomicAdd((unsigned*)(acc + 4), 1u);
        if (done == NB - 1) {
            __threadfence();
            const double topk = atomicAdd(&acc[0], 0.0);   // device-scope reads
            const double pce  = atomicAdd(&acc[1], 0.0);
            const double psl  = atomicAdd(&acc[2], 0.0);
            const double npd  = atomicAdd(&acc[3], 0.0);
            out[0] = (float)(psl / npd);            // smooth_l1 / num_pos
            out[1] = (float)((pce + topk) / npd);   // classification / num_pos
        }
    }
}

extern "C" void kernel_launch(void* const* d_in, const int* in_sizes, int n_in,
                              void* d_out, int out_size, void* d_ws, size_t ws_size,
                              hipStream_t stream)
{
    const float* conf   = (const float*)d_in[0];
    const float* pred   = (const float*)d_in[1];
    const int*   labels = (const int*)d_in[2];
    const float* gt     = (const float*)d_in[3];
    float* out = (float*)d_out;

    double* acc = (double*)d_ws;
    float*  bg  = (float*)((char*)d_ws + BG_OFF);
    float*  lse = (float*)((char*)d_ws + LSE_OFF);

    mb_rows<<<GRID, TPB, 0, stream>>>(conf, bg, lse, acc);
    mb_select<<<NB, 256, 0, stream>>>(conf, pred, gt, labels, bg, lse, acc, out);
}

// Round 8
// 74.203 us; speedup vs baseline: 1.1677x; 1.1677x over previous
//
#include <hip/hip_runtime.h>
#include <math.h>

#define NB 64
#define NP 8732
#define NC 81
#define NROWS (NB * NP)            // 558848 = 2183 * 256 exactly
#define TPB 256
#define NBLK (NROWS / TPB)         // 2183
#define KPT 35                     // ceil(NP/256); i=34 valid only for tid<28

// ws layout:
//   acc      : double[8]        @ 0   [0]=topK_neg [1]=ce_pos [2]=sl1 [3]=num_pos [4]=ticket
//   partials : double[NBLK*3]   @ 64
//   bg       : float[NROWS]     @ BG_OFF
#define PART_OFF 64
#define BG_OFF (PART_OFF + ((NBLK * 3 * 8 + 63) / 64) * 64)

__global__ __launch_bounds__(TPB) void mb_rows(
    const float* __restrict__ conf,
    const float* __restrict__ pred,
    const float* __restrict__ gt,
    const int*   __restrict__ labels,
    float* __restrict__ bg,
    double* __restrict__ partials,
    double* __restrict__ acc)
{
    __shared__ double s_red[4][3];

    const int tid = threadIdx.x;
    const int row = blockIdx.x * TPB + tid;       // always < NROWS (exact grid)

    if (blockIdx.x == 0 && tid == 0) {
        acc[0] = 0.0; acc[1] = 0.0; acc[2] = 0.0; acc[3] = 0.0; acc[4] = 0.0;
    }

    const float* rp = conf + (size_t)row * NC;

    // ---- pure dataflow: 20 (possibly misaligned) float4 + 1 scalar ----
    float4 q[20];
    #pragma unroll
    for (int i = 0; i < 20; ++i) __builtin_memcpy(&q[i], rp + 4 * i, 16);
    const float last = rp[80];

    float4 m4 = q[0];
    #pragma unroll
    for (int i = 1; i < 20; ++i) {                // consumes loads in arrival order
        m4.x = fmaxf(m4.x, q[i].x);
        m4.y = fmaxf(m4.y, q[i].y);
        m4.z = fmaxf(m4.z, q[i].z);
        m4.w = fmaxf(m4.w, q[i].w);
    }
    float M = fmaxf(fmaxf(m4.x, m4.y), fmaxf(m4.z, m4.w));
    M = fmaxf(M, last);

    float s = __expf(last - M);
    #pragma unroll
    for (int i = 0; i < 20; ++i)
        s += __expf(q[i].x - M) + __expf(q[i].y - M)
           + __expf(q[i].z - M) + __expf(q[i].w - M);

    const float lse = M + __logf(s);
    bg[row] = lse - q[0].x;                       // -log_softmax[...,0]

    // ---- per-thread positive tail (loads are ordinary VGPR loads; no queue
    //      to poison — compiler inserts precise waitcnts) ----
    double ce = 0.0, sl = 0.0, npd = 0.0;
    const int lbl = labels[row];
    if (lbl > 0) {
        ce  = (double)(lse - rp[lbl]);            // L1/L2-hot re-read
        npd = 1.0;
        const float4 pv = ((const float4*)pred)[row];
        const float4 gv = ((const float4*)gt)[row];
        float d;
        d = fabsf(pv.x - gv.x); sl += (d < 1.f) ? 0.5f * d * d : d - 0.5f;
        d = fabsf(pv.y - gv.y); sl += (d < 1.f) ? 0.5f * d * d : d - 0.5f;
        d = fabsf(pv.z - gv.z); sl += (d < 1.f) ? 0.5f * d * d : d - 0.5f;
        d = fabsf(pv.w - gv.w); sl += (d < 1.f) ? 0.5f * d * d : d - 0.5f;
    }

    // ---- block reduce -> partials ----
    #pragma unroll
    for (int o = 32; o; o >>= 1) {
        ce  += __shfl_xor(ce, o);
        sl  += __shfl_xor(sl, o);
        npd += __shfl_xor(npd, o);
    }
    const int wid = tid >> 6, lane = tid & 63;
    if (lane == 0) { s_red[wid][0] = ce; s_red[wid][1] = sl; s_red[wid][2] = npd; }
    __syncthreads();
    if (tid == 0) {
        double a = 0, b = 0, c = 0;
        for (int w = 0; w < 4; ++w) { a += s_red[w][0]; b += s_red[w][1]; c += s_red[w][2]; }
        partials[blockIdx.x * 3 + 0] = a;
        partials[blockIdx.x * 3 + 1] = b;
        partials[blockIdx.x * 3 + 2] = c;
    }
}

// One 256-thread block per batch row: stripe-reduce partials into acc[1..3],
// exact top-K sum of bg among negatives (register keys, binary search), and
// the last block through the device-scope ticket writes the outputs.
__global__ __launch_bounds__(256) void mb_select(
    const float* __restrict__ bg,
    const int*   __restrict__ labels,
    const double* __restrict__ partials,
    double* __restrict__ acc,
    float* __restrict__ out)
{
    __shared__ unsigned cnt[32];
    __shared__ unsigned s_u[4][3];
    __shared__ double   s_d[4][3];
    __shared__ unsigned s_K, s_lo, s_hi;

    const int b = blockIdx.x, tid = threadIdx.x;
    const int lane = tid & 63, wid = tid >> 6;

    // ---- (a) stripe-reduce partials: j = b + 64*tid (NBLK = 2183) ----
    {
        double pce = 0, psl = 0, pnp = 0;
        const int j = b + (tid << 6);
        if (tid < KPT && j < NBLK) {
            pce = partials[3 * j + 0];
            psl = partials[3 * j + 1];
            pnp = partials[3 * j + 2];
        }
        #pragma unroll
        for (int o = 32; o; o >>= 1) {
            pce += __shfl_xor(pce, o);
            psl += __shfl_xor(psl, o);
            pnp += __shfl_xor(pnp, o);
        }
        if (lane == 0) { s_d[wid][0] = pce; s_d[wid][1] = psl; s_d[wid][2] = pnp; }
    }

    // ---- (b) keys in registers ----
    unsigned k[KPT];
    unsigned np = 0, maxk = 0u, mink = 0xFFFFFFFFu;
    #pragma unroll
    for (int i = 0; i < KPT; ++i) {
        unsigned key = 0u;
        if (i < 34 || tid < 28) {
            const int idx = i * 256 + tid;
            const int   lbl = labels[b * NP + idx];
            const float vv  = bg[b * NP + idx];
            key = (lbl > 0) ? 0u : (__float_as_uint(vv) + 1u);  // bg>=0: order-preserving
            np += (lbl > 0) ? 1u : 0u;
            if (key) { maxk = max(maxk, key); mink = min(mink, key); }
        }
        k[i] = key;
    }
    for (int i = tid; i < 32; i += 256) cnt[i] = 0u;

    #pragma unroll
    for (int o = 32; o; o >>= 1) {
        np   += __shfl_xor(np, o);
        maxk  = max(maxk, __shfl_xor(maxk, o));
        mink  = min(mink, __shfl_xor(mink, o));
    }
    if (lane == 0) { s_u[wid][0] = np; s_u[wid][1] = maxk; s_u[wid][2] = mink; }
    __syncthreads();

    if (tid == 0) {
        double pce = 0, psl = 0, pnp = 0;
        unsigned npt = 0, mx = 0, mn = 0xFFFFFFFFu;
        for (int q = 0; q < 4; ++q) {
            pce += s_d[q][0]; psl += s_d[q][1]; pnp += s_d[q][2];
            npt += s_u[q][0];
            mx = max(mx, s_u[q][1]); mn = min(mn, s_u[q][2]);
        }
        atomicAdd(&acc[1], pce);
        atomicAdd(&acc[2], psl);
        atomicAdd(&acc[3], pnp);
        unsigned K = 3u * npt;
        const unsigned nneg = NP - npt;
        if (K > nneg) K = nneg;
        s_K = K; s_lo = mn; s_hi = mx;
    }
    __syncthreads();

    const unsigned K = s_K;
    if (K > 0) {
        // smallest x with count(key > x) < K  ->  key of K-th largest
        unsigned lo = s_lo, hi = s_hi;
        int it = 0;
        while (lo < hi) {
            const unsigned mid = lo + ((hi - lo) >> 1);
            unsigned c = 0;
            #pragma unroll
            for (int i = 0; i < KPT; ++i) c += (k[i] > mid) ? 1u : 0u;
            #pragma unroll
            for (int o = 32; o; o >>= 1) c += __shfl_xor(c, o);
            if (lane == 0) atomicAdd(&cnt[it], c);
            __syncthreads();
            if (cnt[it] < K) hi = mid; else lo = mid + 1;
            ++it;
        }
        const unsigned V = lo;            // exact key of K-th largest (>=1)

        double ssum = 0.0; unsigned cgt = 0;
        #pragma unroll
        for (int i = 0; i < KPT; ++i) {
            const unsigned kk = k[i];
            if (kk > V) { ssum += (double)__uint_as_float(kk - 1u); cgt++; }
        }
        #pragma unroll
        for (int o = 32; o; o >>= 1) { ssum += __shfl_xor(ssum, o); cgt += __shfl_xor(cgt, o); }
        if (lane == 0) { s_d[wid][0] = ssum; s_u[wid][0] = cgt; }
        __syncthreads();
        if (tid == 0) {
            double tot = s_d[0][0] + s_d[1][0] + s_d[2][0] + s_d[3][0];
            const unsigned cg = s_u[0][0] + s_u[1][0] + s_u[2][0] + s_u[3][0];
            tot += (double)(K - cg) * (double)__uint_as_float(V - 1u);  // ties at V
            atomicAdd(&acc[0], tot);
        }
    }

    // ---- fused finalization: last block through the ticket writes out ----
    if (tid == 0) {
        __threadfence();
        const unsigned done = atomicAdd((unsigned*)(acc + 4), 1u);
        if (done == NB - 1) {
            __threadfence();
            const double topk = atomicAdd(&acc[0], 0.0);   // device-scope reads
            const double pce  = atomicAdd(&acc[1], 0.0);
            const double psl  = atomicAdd(&acc[2], 0.0);
            const double npd  = atomicAdd(&acc[3], 0.0);
            out[0] = (float)(psl / npd);            // smooth_l1 / num_pos
            out[1] = (float)((pce + topk) / npd);   // classification / num_pos
        }
    }
}

extern "C" void kernel_launch(void* const* d_in, const int* in_sizes, int n_in,
                              void* d_out, int out_size, void* d_ws, size_t ws_size,
                              hipStream_t stream)
{
    const float* conf   = (const float*)d_in[0];
    const float* pred   = (const float*)d_in[1];
    const int*   labels = (const int*)d_in[2];
    const float* gt     = (const float*)d_in[3];
    float* out = (float*)d_out;

    double* acc      = (double*)d_ws;
    double* partials = (double*)((char*)d_ws + PART_OFF);
    float*  bg       = (float*)((char*)d_ws + BG_OFF);

    mb_rows<<<NBLK, TPB, 0, stream>>>(conf, pred, gt, labels, bg, partials, acc);
    mb_select<<<NB, 256, 0, stream>>>(bg, labels, partials, acc, out);
}